// Round 9
// baseline (265.672 us; speedup 1.0000x reference)
//
#include <hip/hip_runtime.h>
#include <math.h>

#define HIDDEN 128
#define IDIM   50000
#define STEPS  100

typedef _Float16 half_t;
typedef _Float16 h2_t __attribute__((ext_vector_type(2)));

// ws layout (float offsets)
#define WS_E1H  0        // 256   e1 partials [2][128]
#define WS_CH   256      // 256   c  partials [2][128]
#define WS_M    512      // 16384 M = W_enc@W_dec (128x128)
#define WS_P    16896    // 49152 P = W_ih@M (384x128)
#define WS_Q    66048    // 384   q = W_ih@(c+b_enc)+b_ih
#define WS_IG1  66432    // 384   ig1 = W_ih@(e1+b_enc)+b_ih
#define WS_HT   66816    // 16384 H_T[i][k] (128x128, cols 0..99 used)

// d_out scratch layout (float offsets). Dead before k_decode writes.
#define SC_PART 0        // 250*16384 = 4.1M floats: M partials

#define NPART   250      // GEMM partial blocks (K-chunk 200)
#define KCHUNK  200

// Fused: blocks 0..249 = M-partial GEMM; blocks 250..505 = encoder dots.
__global__ __launch_bounds__(256, 2) void k_encgemm(const float* __restrict__ W_enc,
    const float* __restrict__ W_dec, const float* __restrict__ x0,
    const float* __restrict__ b_dec, float* __restrict__ ws,
    float* __restrict__ scratch)
{
  __shared__ __align__(16) float smem[1024];
  const int t = threadIdx.x;

  if (blockIdx.x < NPART){
    // ---- M partials: K-chunk of 200; 128x128 tile, 8x8 micro-tile ----
    float (*As)[128] = (float(*)[128])smem;          // [4][128]
    float (*Bs)[128] = (float(*)[128])(smem + 512);  // [4][128]
    const int tx = t & 15, ty = t >> 4;
    const int d0 = blockIdx.x * KCHUNK;
    const int u  = t - 128, ukk = u >> 5, ug = u & 31;
    float acc[8][8];
    #pragma unroll
    for (int p = 0; p < 8; p++)
      #pragma unroll
      for (int q = 0; q < 8; q++) acc[p][q] = 0.f;

    float4 stage;
    if (t < 128) stage = *(const float4*)(W_enc + (size_t)t*IDIM + d0);
    else         stage = *(const float4*)(W_dec + (size_t)(d0+ukk)*HIDDEN + ug*4);

    for (int k0 = 0; k0 < KCHUNK; k0 += 4){
      if (t < 128){
        As[0][t] = stage.x; As[1][t] = stage.y; As[2][t] = stage.z; As[3][t] = stage.w;
      } else {
        *(float4*)&Bs[ukk][ug*4] = stage;
      }
      __syncthreads();
      if (k0 + 4 < KCHUNK){
        if (t < 128) stage = *(const float4*)(W_enc + (size_t)t*IDIM + d0 + k0 + 4);
        else         stage = *(const float4*)(W_dec + (size_t)(d0+k0+4+ukk)*HIDDEN + ug*4);
      }
      #pragma unroll
      for (int kk = 0; kk < 4; kk++){
        float4 alo = *(const float4*)&As[kk][ty*8];
        float4 ahi = *(const float4*)&As[kk][ty*8+4];
        float4 blo = *(const float4*)&Bs[kk][tx*8];
        float4 bhi = *(const float4*)&Bs[kk][tx*8+4];
        float a[8] = {alo.x,alo.y,alo.z,alo.w,ahi.x,ahi.y,ahi.z,ahi.w};
        float b[8] = {blo.x,blo.y,blo.z,blo.w,bhi.x,bhi.y,bhi.z,bhi.w};
        #pragma unroll
        for (int p = 0; p < 8; p++)
          #pragma unroll
          for (int q = 0; q < 8; q++) acc[p][q] += a[p]*b[q];
      }
      __syncthreads();
    }
    float* outp = scratch + (size_t)blockIdx.x * 16384;
    #pragma unroll
    for (int p = 0; p < 8; p++){
      #pragma unroll
      for (int q = 0; q < 8; q += 4){
        *(float4*)&outp[(ty*8+p)*128 + tx*8 + q] =
          make_float4(acc[p][q], acc[p][q+1], acc[p][q+2], acc[p][q+3]);
      }
    }
  } else {
    // ---- encoder: e1p/cp block partials ----
    const int bid  = blockIdx.x - NPART;
    const int r    = bid >> 1;
    const int half = bid & 1;
    float* r0 = smem;         // [256]
    float* r1 = smem + 256;   // [256]
    const float4* wr = (const float4*)(W_enc + (size_t)r*IDIM + half*25000);
    const float4* xv = (const float4*)(x0   + half*25000);
    const float4* bv = (const float4*)(b_dec + half*25000);
    float s0 = 0.f, s1 = 0.f;
    for (int i = t; i < 6250; i += 256){
      float4 w = wr[i]; float4 a = xv[i]; float4 b = bv[i];
      s0 += w.x*a.x + w.y*a.y + w.z*a.z + w.w*a.w;
      s1 += w.x*b.x + w.y*b.y + w.z*b.z + w.w*b.w;
    }
    r0[t] = s0; r1[t] = s1;
    __syncthreads();
    for (int off = 128; off > 0; off >>= 1){
      if (t < off){ r0[t] += r0[t+off]; r1[t] += r1[t+off]; }
      __syncthreads();
    }
    if (t == 0){
      ws[WS_E1H + half*128 + r] = r0[0];
      ws[WS_CH  + half*128 + r] = r1[0];
    }
  }
}

// R9: single fused reduction, 64 blocks x 256 threads; each thread sums all
// 250 partials at its idx straight into M. Replaces reduce1+reduce2 (one
// fewer graph node + no Mp round-trip) AND drops kernel count to 5 so the
// top-5 rocprof table shows EVERY kernel — full per-kernel attribution.
__global__ __launch_bounds__(256) void k_reduceM(const float* __restrict__ scratch,
    float* __restrict__ Mout)
{
  const int idx = blockIdx.x * 256 + threadIdx.x;
  float s[5];
  #pragma unroll
  for (int u = 0; u < 5; u++) s[u] = 0.f;
  for (int p = 0; p < NPART; p += 5){
    #pragma unroll
    for (int u = 0; u < 5; u++)
      s[u] += scratch[(size_t)(p+u)*16384 + idx];
  }
  Mout[idx] = ((s[0]+s[1]) + (s[2]+s[3])) + s[4];
}

// P[r,:] = W_ih[r,:]@M ; q[r] ; ig1[r]. 384 blocks x 128 threads.
__global__ __launch_bounds__(128) void k_smallP(const float* __restrict__ W_ih,
    const float* __restrict__ b_ih, const float* __restrict__ b_enc,
    const float* __restrict__ ws, const float* __restrict__ M,
    float* __restrict__ P, float* __restrict__ q, float* __restrict__ ig1)
{
  const int r = blockIdx.x, j = threadIdx.x;
  const float* wr = W_ih + (size_t)r * HIDDEN;
  float acc = 0.f;
  #pragma unroll 8
  for (int k = 0; k < HIDDEN; k++) acc += wr[k] * M[k*HIDDEN + j];
  P[(size_t)r*HIDDEN + j] = acc;
  const float wj = wr[j];
  float cj  = ws[WS_CH  + j] + ws[WS_CH  + 128 + j];
  float e1j = ws[WS_E1H + j] + ws[WS_E1H + 128 + j];
  float t0 = wj * (cj  + b_enc[j]);
  float t1 = wj * (e1j + b_enc[j]);
  __shared__ float r0[128], r1[128];
  r0[j] = t0; r1[j] = t1;
  __syncthreads();
  for (int off = 64; off > 0; off >>= 1){
    if (j < off){ r0[j] += r0[j+off]; r1[j] += r1[j+off]; }
    __syncthreads();
  }
  if (j == 0){
    q[r]   = r0[0] + b_ih[r];
    ig1[r] = r1[0] + b_ih[r];
  }
}

// ---- fast transcendentals ----
__device__ __forceinline__ float fexp2_(float x){ return __builtin_amdgcn_exp2f(x); }
__device__ __forceinline__ float frcp_(float x){ return __builtin_amdgcn_rcpf(x); }
__device__ __forceinline__ float fsig_(float x){
  return frcp_(1.f + fexp2_(x * -1.44269504f));
}
__device__ __forceinline__ float ftanh_(float x){
  return 1.f - 2.f * frcp_(fexp2_(x * 2.88539008f) + 1.f);
}
__device__ __forceinline__ float dppx1_(float x){
  return __builtin_bit_cast(float,
      __builtin_amdgcn_mov_dpp(__builtin_bit_cast(int, x), 0xB1, 0xF, 0xF, true));
}

// Sequential recurrence — R5 measured optimum (71.5us), unchanged.
__global__
__attribute__((amdgpu_flat_work_group_size(256, 256), amdgpu_waves_per_eu(1, 1)))
void k_recur(const float* __restrict__ P,
    const float* __restrict__ W_hh, const float* __restrict__ q,
    const float* __restrict__ b_n, const float* __restrict__ ig1,
    float* __restrict__ H_T)
{
  const int t = threadIdx.x;
  const int e = t >> 1;          // hidden element 0..127
  const int p = t & 1;           // k-half within the pair

  const float* rP0 = P    + (size_t)e         * HIDDEN + p*64;
  const float* rP1 = P    + (size_t)(128 + e) * HIDDEN + p*64;
  const float* rP2 = P    + (size_t)(256 + e) * HIDDEN + p*64;
  const float* rH0 = W_hh + (size_t)e         * HIDDEN + p*64;
  const float* rH1 = W_hh + (size_t)(128 + e) * HIDDEN + p*64;
  const float* rH2 = W_hh + (size_t)(256 + e) * HIDDEN + p*64;

  const float qa = p ? 0.f : q[e];
  const float qb = p ? 0.f : q[128 + e];
  const float qc = p ? 0.f : q[256 + e];

  h2_t wP0[32], wP1[32], wP2[32], wH0[32], wH1[32], wH2[32];
#define LOADROW(DST, SRC)                                                     \
  { const float4* f = (const float4*)(SRC);                                   \
    _Pragma("unroll")                                                         \
    for (int j = 0; j < 16; j++){                                             \
      float4 v = f[j];                                                        \
      h2_t w;                                                                 \
      w.x=(half_t)v.x; w.y=(half_t)v.y; DST[2*j]   = w;                       \
      w.x=(half_t)v.z; w.y=(half_t)v.w; DST[2*j+1] = w;                       \
    } }
  LOADROW(wP0, rP0); LOADROW(wP1, rP1); LOADROW(wP2, rP2);
  LOADROW(wH0, rH0); LOADROW(wH1, rH1); LOADROW(wH2, rH2);
#undef LOADROW

  __shared__ __align__(16) half_t h16[2][HIDDEN];   // double-buffered broadcast
  __shared__ float Hs[128 * 101];                   // h history, padded rows

  const float bn = b_n[e];
  float h;
  {
    float reset = fsig_(ig1[e]);
    float inp   = fsig_(ig1[128 + e]);
    float nw    = ftanh_(ig1[256 + e] + reset * bn);
    h = nw - inp * nw;
  }
  if (!p) h16[0][e] = (half_t)h;
  else    Hs[e * 101] = h;
  __syncthreads();

#define RSTEP(KK, RD, WR)                                                     \
  {                                                                           \
    const uint4* hq = ((const uint4*)(h16[RD])) + p*8;                        \
    float a0 = qa,  a1 = 0.f;                                                 \
    float b0 = qb,  b1 = 0.f;                                                 \
    float c0 = qc,  c1 = 0.f;                                                 \
    float d0 = 0.f, d1 = 0.f;                                                 \
    float g0 = 0.f, g1 = 0.f;                                                 \
    float f0 = 0.f, f1 = 0.f;                                                 \
    _Pragma("unroll")                                                         \
    for (int jj = 0; jj < 8; jj++){                                           \
      uint4 hb = hq[jj];                                                      \
      h2_t hx = __builtin_bit_cast(h2_t, hb.x);                               \
      h2_t hy = __builtin_bit_cast(h2_t, hb.y);                               \
      h2_t hz = __builtin_bit_cast(h2_t, hb.z);                               \
      h2_t hw = __builtin_bit_cast(h2_t, hb.w);                               \
      a0 = __builtin_amdgcn_fdot2(wP0[4*jj+0], hx, a0, false);                \
      a1 = __builtin_amdgcn_fdot2(wP0[4*jj+1], hy, a1, false);                \
      a0 = __builtin_amdgcn_fdot2(wP0[4*jj+2], hz, a0, false);                \
      a1 = __builtin_amdgcn_fdot2(wP0[4*jj+3], hw, a1, false);                \
      b0 = __builtin_amdgcn_fdot2(wP1[4*jj+0], hx, b0, false);                \
      b1 = __builtin_amdgcn_fdot2(wP1[4*jj+1], hy, b1, false);                \
      b0 = __builtin_amdgcn_fdot2(wP1[4*jj+2], hz, b0, false);                \
      b1 = __builtin_amdgcn_fdot2(wP1[4*jj+3], hw, b1, false);                \
      c0 = __builtin_amdgcn_fdot2(wP2[4*jj+0], hx, c0, false);                \
      c1 = __builtin_amdgcn_fdot2(wP2[4*jj+1], hy, c1, false);                \
      c0 = __builtin_amdgcn_fdot2(wP2[4*jj+2], hz, c0, false);                \
      c1 = __builtin_amdgcn_fdot2(wP2[4*jj+3], hw, c1, false);                \
      d0 = __builtin_amdgcn_fdot2(wH0[4*jj+0], hx, d0, false);                \
      d1 = __builtin_amdgcn_fdot2(wH0[4*jj+1], hy, d1, false);                \
      d0 = __builtin_amdgcn_fdot2(wH0[4*jj+2], hz, d0, false);                \
      d1 = __builtin_amdgcn_fdot2(wH0[4*jj+3], hw, d1, false);                \
      g0 = __builtin_amdgcn_fdot2(wH1[4*jj+0], hx, g0, false);                \
      g1 = __builtin_amdgcn_fdot2(wH1[4*jj+1], hy, g1, false);                \
      g0 = __builtin_amdgcn_fdot2(wH1[4*jj+2], hz, g0, false);                \
      g1 = __builtin_amdgcn_fdot2(wH1[4*jj+3], hw, g1, false);                \
      f0 = __builtin_amdgcn_fdot2(wH2[4*jj+0], hx, f0, false);                \
      f1 = __builtin_amdgcn_fdot2(wH2[4*jj+1], hy, f1, false);                \
      f0 = __builtin_amdgcn_fdot2(wH2[4*jj+2], hz, f0, false);                \
      f1 = __builtin_amdgcn_fdot2(wH2[4*jj+3], hw, f1, false);                \
    }                                                                         \
    float A = a0 + a1, B = b0 + b1, C = c0 + c1;                              \
    float D = d0 + d1, G = g0 + g1, F = f0 + f1;                              \
    A += dppx1_(A); B += dppx1_(B); C += dppx1_(C);                           \
    D += dppx1_(D); G += dppx1_(G); F += dppx1_(F);                           \
    float rs = fsig_(A + D);                                                  \
    float ip = fsig_(B + G);                                                  \
    float nw = ftanh_(C + rs * (F + bn));                                     \
    h = nw + ip * (h - nw);                                                   \
    if (!p) h16[WR][e] = (half_t)h;                                           \
    else    Hs[e * 101 + (KK)] = h;                                           \
    __syncthreads();                                                          \
  }

  for (int k = 1; k < STEPS - 1; k += 2){
    RSTEP(k,     0, 1);
    RSTEP(k + 1, 1, 0);
  }
  RSTEP(STEPS - 1, 0, 1); // k = 99
#undef RSTEP

  // Coalesced dump: H_T[e*128 + k] = Hs[e][k] (k<100), 0 otherwise.
  for (int i = 0; i < 64; i++){
    int f = i * 256 + t;
    int ee = f >> 7, kk = f & 127;
    H_T[f] = (kk < STEPS) ? Hs[ee * 101 + kk] : 0.f;
  }
}

// X[k][d] = W_dec[d,:]@h_k + b_dec[d].
// Wave-uniform H reads via the SCALAR path (R7).
__global__ __launch_bounds__(256, 4) void k_decode(const float* __restrict__ W_dec,
    const float* __restrict__ b_dec, const float* __restrict__ H_T,
    float* __restrict__ out)
{
  __shared__ float Ws[64 * 129];   // 33024 B
  const int t    = threadIdx.x;
  const int lane = t & 63;
  const int wv   = __builtin_amdgcn_readfirstlane(t >> 6);  // wave id 0..3
  const int d0   = blockIdx.x * 64;
  const int d    = d0 + lane;

  #pragma unroll
  for (int i = 0; i < 8; i++){
    int f4 = i * 256 + t;          // 0..2047 float4s
    int rl = f4 >> 5;              // local row 0..63
    int cl = (f4 & 31) * 4;        // col 0,4,..,124
    int rg = d0 + rl;
    float4 v = *(const float4*)&W_dec[(size_t)((rg < IDIM) ? rg : (IDIM-1))*HIDDEN + cl];
    Ws[rl*129 + cl + 0] = v.x;
    Ws[rl*129 + cl + 1] = v.y;
    Ws[rl*129 + cl + 2] = v.z;
    Ws[rl*129 + cl + 3] = v.w;
  }
  __syncthreads();

  const int k0 = wv * 25;          // this wave's k-range [k0, k0+25)
  float acc[25];
  #pragma unroll
  for (int k = 0; k < 25; k++) acc[k] = 0.f;

  const float* wrow = &Ws[lane * 129];
  #pragma unroll 2
  for (int j = 0; j < HIDDEN; j++){
    float w = wrow[j];                               // ds_read_b32, conflict-free
    const float* hp = &H_T[j * HIDDEN + k0];         // wave-uniform address
    #pragma unroll
    for (int k = 0; k < 25; k++)
      acc[k] = fmaf(w, hp[k], acc[k]);               // v_fmac with SGPR operand
  }

  if (d < IDIM){
    const float bd = b_dec[d];
    const size_t SO = (size_t)STEPS * IDIM;  // 5,000,000
    #pragma unroll
    for (int k = 0; k < 25; k++){
      float v = acc[k] + bd;
      size_t o = (size_t)(k0 + k) * IDIM + d;        // 64 lanes -> 256B contiguous
      out[o]        = v;     // samples
      out[o + SO]   = v;     // means
      out[o + 2*SO] = 0.f;   // sigmas
    }
  }
}

extern "C" void kernel_launch(void* const* d_in, const int* in_sizes, int n_in,
                              void* d_out, int out_size, void* d_ws, size_t ws_size,
                              hipStream_t stream) {
  const float* x0    = (const float*)d_in[0];
  const float* W_enc = (const float*)d_in[1];
  const float* b_enc = (const float*)d_in[2];
  const float* W_ih  = (const float*)d_in[3];
  const float* W_hh  = (const float*)d_in[4];
  const float* b_ih  = (const float*)d_in[5];
  const float* b_n   = (const float*)d_in[6];
  const float* W_dec = (const float*)d_in[7];
  const float* b_dec = (const float*)d_in[8];
  (void)in_sizes; (void)n_in; (void)out_size; (void)ws_size;

  float* out = (float*)d_out;
  float* ws  = (float*)d_ws;
  float* M   = ws + WS_M;
  float* P   = ws + WS_P;
  float* q   = ws + WS_Q;
  float* ig1 = ws + WS_IG1;
  float* H_T = ws + WS_HT;
  float* scratch = out + SC_PART;  // 16.4 MB of d_out, dead until k_decode

  hipLaunchKernelGGL(k_encgemm, dim3(506), dim3(256), 0, stream, W_enc, W_dec, x0, b_dec, ws, scratch);
  hipLaunchKernelGGL(k_reduceM, dim3(64),  dim3(256), 0, stream, scratch, M);
  hipLaunchKernelGGL(k_smallP,  dim3(384), dim3(128), 0, stream, W_ih, b_ih, b_enc, ws, M, P, q, ig1);
  hipLaunchKernelGGL(k_recur,   dim3(1),   dim3(256), 0, stream, P, W_hh, q, b_n, ig1, H_T);
  hipLaunchKernelGGL(k_decode,  dim3(782), dim3(256), 0, stream, W_dec, b_dec, H_T, out);
}

// Round 10
// 250.052 us; speedup vs baseline: 1.0625x; 1.0625x over previous
//
#include <hip/hip_runtime.h>
#include <math.h>

#define HIDDEN 128
#define IDIM   50000
#define STEPS  100

typedef _Float16 half_t;
typedef _Float16 h2_t __attribute__((ext_vector_type(2)));

// ws layout (float offsets)
#define WS_E1H  0        // 256   e1 partials [2][128]
#define WS_CH   256      // 256   c  partials [2][128]
#define WS_M    512      // 16384 M = W_enc@W_dec (128x128)
#define WS_P    16896    // 49152 P = W_ih@M (384x128)
#define WS_Q    66048    // 384   q = W_ih@(c+b_enc)+b_ih
#define WS_IG1  66432    // 384   ig1 = W_ih@(e1+b_enc)+b_ih
#define WS_HT   66816    // 16384 H_T[i][k] (128x128, cols 0..99 used)

// d_out scratch layout (float offsets). All dead before k_decode writes.
// R10: front reverted to the R7 measured-best config (500 partials, K=100,
// reduce1+reduce2). R8's K=200 re-tile (+4us) and R9's 64-block fused
// reduce (+10us, latency-bound at 25% CU coverage) both regressed.
#define SC_PART 0        // 500*16384 = 8.19M floats: M partials
#define SC_MP   9000000  // 10*16384 floats: stage-1 reduced partials

// Fused: blocks 0..499 = M-partial GEMM; blocks 500..755 = encoder dots.
__global__ __launch_bounds__(256, 2) void k_encgemm(const float* __restrict__ W_enc,
    const float* __restrict__ W_dec, const float* __restrict__ x0,
    const float* __restrict__ b_dec, float* __restrict__ ws,
    float* __restrict__ scratch)
{
  __shared__ __align__(16) float smem[1024];
  const int t = threadIdx.x;

  if (blockIdx.x < 500){
    // ---- M partials: K-chunk of 100; 128x128 tile, 8x8 micro-tile ----
    float (*As)[128] = (float(*)[128])smem;          // [4][128]
    float (*Bs)[128] = (float(*)[128])(smem + 512);  // [4][128]
    const int tx = t & 15, ty = t >> 4;
    const int d0 = blockIdx.x * 100;
    const int u  = t - 128, ukk = u >> 5, ug = u & 31;
    float acc[8][8];
    #pragma unroll
    for (int p = 0; p < 8; p++)
      #pragma unroll
      for (int q = 0; q < 8; q++) acc[p][q] = 0.f;

    float4 stage;
    if (t < 128) stage = *(const float4*)(W_enc + (size_t)t*IDIM + d0);
    else         stage = *(const float4*)(W_dec + (size_t)(d0+ukk)*HIDDEN + ug*4);

    for (int k0 = 0; k0 < 100; k0 += 4){
      if (t < 128){
        As[0][t] = stage.x; As[1][t] = stage.y; As[2][t] = stage.z; As[3][t] = stage.w;
      } else {
        *(float4*)&Bs[ukk][ug*4] = stage;
      }
      __syncthreads();
      if (k0 + 4 < 100){
        if (t < 128) stage = *(const float4*)(W_enc + (size_t)t*IDIM + d0 + k0 + 4);
        else         stage = *(const float4*)(W_dec + (size_t)(d0+k0+4+ukk)*HIDDEN + ug*4);
      }
      #pragma unroll
      for (int kk = 0; kk < 4; kk++){
        float4 alo = *(const float4*)&As[kk][ty*8];
        float4 ahi = *(const float4*)&As[kk][ty*8+4];
        float4 blo = *(const float4*)&Bs[kk][tx*8];
        float4 bhi = *(const float4*)&Bs[kk][tx*8+4];
        float a[8] = {alo.x,alo.y,alo.z,alo.w,ahi.x,ahi.y,ahi.z,ahi.w};
        float b[8] = {blo.x,blo.y,blo.z,blo.w,bhi.x,bhi.y,bhi.z,bhi.w};
        #pragma unroll
        for (int p = 0; p < 8; p++)
          #pragma unroll
          for (int q = 0; q < 8; q++) acc[p][q] += a[p]*b[q];
      }
      __syncthreads();
    }
    float* outp = scratch + (size_t)blockIdx.x * 16384;
    #pragma unroll
    for (int p = 0; p < 8; p++){
      #pragma unroll
      for (int q = 0; q < 8; q += 4){
        *(float4*)&outp[(ty*8+p)*128 + tx*8 + q] =
          make_float4(acc[p][q], acc[p][q+1], acc[p][q+2], acc[p][q+3]);
      }
    }
  } else {
    // ---- encoder: e1p/cp block partials ----
    const int bid  = blockIdx.x - 500;
    const int r    = bid >> 1;
    const int half = bid & 1;
    float* r0 = smem;         // [256]
    float* r1 = smem + 256;   // [256]
    const float4* wr = (const float4*)(W_enc + (size_t)r*IDIM + half*25000);
    const float4* xv = (const float4*)(x0   + half*25000);
    const float4* bv = (const float4*)(b_dec + half*25000);
    float s0 = 0.f, s1 = 0.f;
    for (int i = t; i < 6250; i += 256){
      float4 w = wr[i]; float4 a = xv[i]; float4 b = bv[i];
      s0 += w.x*a.x + w.y*a.y + w.z*a.z + w.w*a.w;
      s1 += w.x*b.x + w.y*b.y + w.z*b.z + w.w*b.w;
    }
    r0[t] = s0; r1[t] = s1;
    __syncthreads();
    for (int off = 128; off > 0; off >>= 1){
      if (t < off){ r0[t] += r0[t+off]; r1[t] += r1[t+off]; }
      __syncthreads();
    }
    if (t == 0){
      ws[WS_E1H + half*128 + r] = r0[0];
      ws[WS_CH  + half*128 + r] = r1[0];
    }
  }
}

// Stage 1: 640 blocks; block (chunk, g) sums partials g*50..g*50+49.
__global__ __launch_bounds__(256) void k_reduce1(const float* __restrict__ scratch,
    float* __restrict__ Mp)
{
  const int g     = blockIdx.x % 10;
  const int chunk = blockIdx.x / 10;
  const int idx   = chunk * 256 + threadIdx.x;
  const float* base = scratch + (size_t)(g*50) * 16384 + idx;
  float s[10];
  #pragma unroll
  for (int uu = 0; uu < 10; uu++) s[uu] = 0.f;
  for (int p = 0; p < 50; p += 10){
    #pragma unroll
    for (int uu = 0; uu < 10; uu++)
      s[uu] += base[(size_t)(p+uu)*16384];
  }
  float t0 = (s[0]+s[1]) + (s[2]+s[3]);
  float t1 = (s[4]+s[5]) + (s[6]+s[7]);
  Mp[(size_t)g*16384 + idx] = t0 + t1 + (s[8]+s[9]);
}

// Stage 2: 64 blocks, sum 10 -> M.
__global__ __launch_bounds__(256) void k_reduce2(const float* __restrict__ Mp,
    float* __restrict__ Mout)
{
  const int idx = blockIdx.x * 256 + threadIdx.x;
  float s = 0.f;
  #pragma unroll
  for (int g = 0; g < 10; g++) s += Mp[(size_t)g*16384 + idx];
  Mout[idx] = s;
}

// P[r,:] = W_ih[r,:]@M ; q[r] ; ig1[r]. 384 blocks x 128 threads.
__global__ __launch_bounds__(128) void k_smallP(const float* __restrict__ W_ih,
    const float* __restrict__ b_ih, const float* __restrict__ b_enc,
    const float* __restrict__ ws, const float* __restrict__ M,
    float* __restrict__ P, float* __restrict__ q, float* __restrict__ ig1)
{
  const int r = blockIdx.x, j = threadIdx.x;
  const float* wr = W_ih + (size_t)r * HIDDEN;
  float acc = 0.f;
  #pragma unroll 8
  for (int k = 0; k < HIDDEN; k++) acc += wr[k] * M[k*HIDDEN + j];
  P[(size_t)r*HIDDEN + j] = acc;
  const float wj = wr[j];
  float cj  = ws[WS_CH  + j] + ws[WS_CH  + 128 + j];
  float e1j = ws[WS_E1H + j] + ws[WS_E1H + 128 + j];
  float t0 = wj * (cj  + b_enc[j]);
  float t1 = wj * (e1j + b_enc[j]);
  __shared__ float r0[128], r1[128];
  r0[j] = t0; r1[j] = t1;
  __syncthreads();
  for (int off = 64; off > 0; off >>= 1){
    if (j < off){ r0[j] += r0[j+off]; r1[j] += r1[j+off]; }
    __syncthreads();
  }
  if (j == 0){
    q[r]   = r0[0] + b_ih[r];
    ig1[r] = r1[0] + b_ih[r];
  }
}

// ---- fast transcendentals ----
__device__ __forceinline__ float fexp2_(float x){ return __builtin_amdgcn_exp2f(x); }
__device__ __forceinline__ float frcp_(float x){ return __builtin_amdgcn_rcpf(x); }
__device__ __forceinline__ float fsig_(float x){
  return frcp_(1.f + fexp2_(x * -1.44269504f));
}
__device__ __forceinline__ float ftanh_(float x){
  return 1.f - 2.f * frcp_(fexp2_(x * 2.88539008f) + 1.f);
}
__device__ __forceinline__ float dppx1_(float x){
  return __builtin_bit_cast(float,
      __builtin_amdgcn_mov_dpp(__builtin_bit_cast(int, x), 0xB1, 0xF, 0xF, true));
}

// Sequential recurrence, R5 structure (4 waves, 2-way k-split, 1 barrier/step,
// LDS history). R10 change: INTERLEAVED fdot2 ordering. Old order updated the
// same accumulator at instruction distance 2 (a0 at slots 0 and 2 of each jj
// block) — ~8 cyc apart at ~4cyc issue, far below fdot2 result latency, so
// every pair stalled; 96 such pairs/step ≈ the ~865 cyc/step of non-issue time
// (VALUBusy 50%). New order goes word-major across all 6 rows: same-acc
// distance 12 instrs (~48 cyc) > latency. Pure scheduling change, same math.
__global__
__attribute__((amdgpu_flat_work_group_size(256, 256), amdgpu_waves_per_eu(1, 1)))
void k_recur(const float* __restrict__ P,
    const float* __restrict__ W_hh, const float* __restrict__ q,
    const float* __restrict__ b_n, const float* __restrict__ ig1,
    float* __restrict__ H_T)
{
  const int t = threadIdx.x;
  const int e = t >> 1;          // hidden element 0..127
  const int p = t & 1;           // k-half within the pair

  const float* rP0 = P    + (size_t)e         * HIDDEN + p*64;
  const float* rP1 = P    + (size_t)(128 + e) * HIDDEN + p*64;
  const float* rP2 = P    + (size_t)(256 + e) * HIDDEN + p*64;
  const float* rH0 = W_hh + (size_t)e         * HIDDEN + p*64;
  const float* rH1 = W_hh + (size_t)(128 + e) * HIDDEN + p*64;
  const float* rH2 = W_hh + (size_t)(256 + e) * HIDDEN + p*64;

  const float qa = p ? 0.f : q[e];
  const float qb = p ? 0.f : q[128 + e];
  const float qc = p ? 0.f : q[256 + e];

  h2_t wP0[32], wP1[32], wP2[32], wH0[32], wH1[32], wH2[32];
#define LOADROW(DST, SRC)                                                     \
  { const float4* f = (const float4*)(SRC);                                   \
    _Pragma("unroll")                                                         \
    for (int j = 0; j < 16; j++){                                             \
      float4 v = f[j];                                                        \
      h2_t w;                                                                 \
      w.x=(half_t)v.x; w.y=(half_t)v.y; DST[2*j]   = w;                       \
      w.x=(half_t)v.z; w.y=(half_t)v.w; DST[2*j+1] = w;                       \
    } }
  LOADROW(wP0, rP0); LOADROW(wP1, rP1); LOADROW(wP2, rP2);
  LOADROW(wH0, rH0); LOADROW(wH1, rH1); LOADROW(wH2, rH2);
#undef LOADROW

  __shared__ __align__(16) half_t h16[2][HIDDEN];   // double-buffered broadcast
  __shared__ float Hs[128 * 101];                   // h history, padded rows

  const float bn = b_n[e];
  float h;
  {
    float reset = fsig_(ig1[e]);
    float inp   = fsig_(ig1[128 + e]);
    float nw    = ftanh_(ig1[256 + e] + reset * bn);
    h = nw - inp * nw;
  }
  if (!p) h16[0][e] = (half_t)h;
  else    Hs[e * 101] = h;
  __syncthreads();

#define FD(ACC, W, H) ACC = __builtin_amdgcn_fdot2((W), (H), ACC, false)
#define RSTEP(KK, RD, WR)                                                     \
  {                                                                           \
    const uint4* hq = ((const uint4*)(h16[RD])) + p*8;                        \
    float a0 = qa,  a1 = 0.f;                                                 \
    float b0 = qb,  b1 = 0.f;                                                 \
    float c0 = qc,  c1 = 0.f;                                                 \
    float d0 = 0.f, d1 = 0.f;                                                 \
    float g0 = 0.f, g1 = 0.f;                                                 \
    float f0 = 0.f, f1 = 0.f;                                                 \
    _Pragma("unroll")                                                         \
    for (int jj = 0; jj < 8; jj++){                                           \
      uint4 hb = hq[jj];                                                      \
      h2_t hx = __builtin_bit_cast(h2_t, hb.x);                               \
      h2_t hy = __builtin_bit_cast(h2_t, hb.y);                               \
      h2_t hz = __builtin_bit_cast(h2_t, hb.z);                               \
      h2_t hw = __builtin_bit_cast(h2_t, hb.w);                               \
      /* word x: all six *0 chains */                                         \
      FD(a0, wP0[4*jj+0], hx); FD(b0, wP1[4*jj+0], hx);                       \
      FD(c0, wP2[4*jj+0], hx); FD(d0, wH0[4*jj+0], hx);                       \
      FD(g0, wH1[4*jj+0], hx); FD(f0, wH2[4*jj+0], hx);                       \
      /* word y: all six *1 chains */                                         \
      FD(a1, wP0[4*jj+1], hy); FD(b1, wP1[4*jj+1], hy);                       \
      FD(c1, wP2[4*jj+1], hy); FD(d1, wH0[4*jj+1], hy);                       \
      FD(g1, wH1[4*jj+1], hy); FD(f1, wH2[4*jj+1], hy);                       \
      /* word z: *0 chains again, 12 instrs since last touch */               \
      FD(a0, wP0[4*jj+2], hz); FD(b0, wP1[4*jj+2], hz);                       \
      FD(c0, wP2[4*jj+2], hz); FD(d0, wH0[4*jj+2], hz);                       \
      FD(g0, wH1[4*jj+2], hz); FD(f0, wH2[4*jj+2], hz);                       \
      /* word w: *1 chains again */                                           \
      FD(a1, wP0[4*jj+3], hw); FD(b1, wP1[4*jj+3], hw);                       \
      FD(c1, wP2[4*jj+3], hw); FD(d1, wH0[4*jj+3], hw);                       \
      FD(g1, wH1[4*jj+3], hw); FD(f1, wH2[4*jj+3], hw);                       \
    }                                                                         \
    float A = a0 + a1, B = b0 + b1, C = c0 + c1;                              \
    float D = d0 + d1, G = g0 + g1, F = f0 + f1;                              \
    A += dppx1_(A); B += dppx1_(B); C += dppx1_(C);                           \
    D += dppx1_(D); G += dppx1_(G); F += dppx1_(F);                           \
    float rs = fsig_(A + D);                                                  \
    float ip = fsig_(B + G);                                                  \
    float nw = ftanh_(C + rs * (F + bn));                                     \
    h = nw + ip * (h - nw);                                                   \
    if (!p) h16[WR][e] = (half_t)h;                                           \
    else    Hs[e * 101 + (KK)] = h;                                           \
    __syncthreads();                                                          \
  }

  for (int k = 1; k < STEPS - 1; k += 2){
    RSTEP(k,     0, 1);
    RSTEP(k + 1, 1, 0);
  }
  RSTEP(STEPS - 1, 0, 1); // k = 99
#undef RSTEP
#undef FD

  // Coalesced dump: H_T[e*128 + k] = Hs[e][k] (k<100), 0 otherwise.
  for (int i = 0; i < 64; i++){
    int f = i * 256 + t;
    int ee = f >> 7, kk = f & 127;
    H_T[f] = (kk < STEPS) ? Hs[ee * 101 + kk] : 0.f;
  }
}

// X[k][d] = W_dec[d,:]@h_k + b_dec[d].
// Wave-uniform H reads via the SCALAR path (R7, measured best).
__global__ __launch_bounds__(256, 4) void k_decode(const float* __restrict__ W_dec,
    const float* __restrict__ b_dec, const float* __restrict__ H_T,
    float* __restrict__ out)
{
  __shared__ float Ws[64 * 129];   // 33024 B
  const int t    = threadIdx.x;
  const int lane = t & 63;
  const int wv   = __builtin_amdgcn_readfirstlane(t >> 6);  // wave id 0..3
  const int d0   = blockIdx.x * 64;
  const int d    = d0 + lane;

  #pragma unroll
  for (int i = 0; i < 8; i++){
    int f4 = i * 256 + t;          // 0..2047 float4s
    int rl = f4 >> 5;              // local row 0..63
    int cl = (f4 & 31) * 4;        // col 0,4,..,124
    int rg = d0 + rl;
    float4 v = *(const float4*)&W_dec[(size_t)((rg < IDIM) ? rg : (IDIM-1))*HIDDEN + cl];
    Ws[rl*129 + cl + 0] = v.x;
    Ws[rl*129 + cl + 1] = v.y;
    Ws[rl*129 + cl + 2] = v.z;
    Ws[rl*129 + cl + 3] = v.w;
  }
  __syncthreads();

  const int k0 = wv * 25;          // this wave's k-range [k0, k0+25)
  float acc[25];
  #pragma unroll
  for (int k = 0; k < 25; k++) acc[k] = 0.f;

  const float* wrow = &Ws[lane * 129];
  #pragma unroll 2
  for (int j = 0; j < HIDDEN; j++){
    float w = wrow[j];                               // ds_read_b32, conflict-free
    const float* hp = &H_T[j * HIDDEN + k0];         // wave-uniform address
    #pragma unroll
    for (int k = 0; k < 25; k++)
      acc[k] = fmaf(w, hp[k], acc[k]);               // v_fmac with SGPR operand
  }

  if (d < IDIM){
    const float bd = b_dec[d];
    const size_t SO = (size_t)STEPS * IDIM;  // 5,000,000
    #pragma unroll
    for (int k = 0; k < 25; k++){
      float v = acc[k] + bd;
      size_t o = (size_t)(k0 + k) * IDIM + d;        // 64 lanes -> 256B contiguous
      out[o]        = v;     // samples
      out[o + SO]   = v;     // means
      out[o + 2*SO] = 0.f;   // sigmas
    }
  }
}

extern "C" void kernel_launch(void* const* d_in, const int* in_sizes, int n_in,
                              void* d_out, int out_size, void* d_ws, size_t ws_size,
                              hipStream_t stream) {
  const float* x0    = (const float*)d_in[0];
  const float* W_enc = (const float*)d_in[1];
  const float* b_enc = (const float*)d_in[2];
  const float* W_ih  = (const float*)d_in[3];
  const float* W_hh  = (const float*)d_in[4];
  const float* b_ih  = (const float*)d_in[5];
  const float* b_n   = (const float*)d_in[6];
  const float* W_dec = (const float*)d_in[7];
  const float* b_dec = (const float*)d_in[8];
  (void)in_sizes; (void)n_in; (void)out_size; (void)ws_size;

  float* out = (float*)d_out;
  float* ws  = (float*)d_ws;
  float* M   = ws + WS_M;
  float* P   = ws + WS_P;
  float* q   = ws + WS_Q;
  float* ig1 = ws + WS_IG1;
  float* H_T = ws + WS_HT;
  float* scratch = out + SC_PART;  // 32 MB of d_out, dead until k_decode
  float* Mp      = out + SC_MP;    // 640 KB of d_out, ditto

  hipLaunchKernelGGL(k_encgemm, dim3(756), dim3(256), 0, stream, W_enc, W_dec, x0, b_dec, ws, scratch);
  hipLaunchKernelGGL(k_reduce1, dim3(640), dim3(256), 0, stream, scratch, Mp);
  hipLaunchKernelGGL(k_reduce2, dim3(64),  dim3(256), 0, stream, Mp, M);
  hipLaunchKernelGGL(k_smallP,  dim3(384), dim3(128), 0, stream, W_ih, b_ih, b_enc, ws, M, P, q, ig1);
  hipLaunchKernelGGL(k_recur,   dim3(1),   dim3(256), 0, stream, P, W_hh, q, b_n, ig1, H_T);
  hipLaunchKernelGGL(k_decode,  dim3(782), dim3(256), 0, stream, W_dec, b_dec, H_T, out);
}